// Round 5
// baseline (511.980 us; speedup 1.0000x reference)
//
#include <hip/hip_runtime.h>

#define NL   4
#define NH   4
#define HD   64
#define CD   256
#define SQL  1024
#define BB   16

typedef _Float16 half8 __attribute__((ext_vector_type(8)));
typedef _Float16 half4 __attribute__((ext_vector_type(4)));
typedef float    f32x4 __attribute__((ext_vector_type(4)));
typedef unsigned short u16x8 __attribute__((ext_vector_type(8)));

static __device__ __forceinline__ float bf2f(unsigned short u) {
    union { unsigned int i; float f; } v; v.i = ((unsigned int)u) << 16; return v.f;
}
static __device__ __forceinline__ unsigned short f2bf(float f) {
    union { float f; unsigned int i; } v; v.f = f;
    unsigned int u = v.i;
    return (unsigned short)((u + 0x7fffu + ((u >> 16) & 1u)) >> 16);
}

// ---------- dtype detector: inputs packed bf16 (flag=1) or f32 (flag=0)? ----------
__global__ void detect_dtype(const unsigned int* __restrict__ w, int* __restrict__ flag) {
    if (threadIdx.x == 0 && blockIdx.x == 0) {
        int cnt = 0;
        for (int i = 0; i < 64; i++) {
            unsigned int lo = w[i] & 0xFFFFu;
            int e = (int)((lo >> 7) & 0xFF);
            if (e >= 96 && e <= 144) cnt++;
        }
        *flag = (cnt >= 48) ? 1 : 0;
    }
}

// ---------- prep: kv -> f16 copy + transposed copy kvT[i][h][d][l] ----------
__global__ void prep_kv(const void* __restrict__ kvin,
                        _Float16* __restrict__ kv16, _Float16* __restrict__ kvT16,
                        const int* __restrict__ flag) {
    __shared__ __align__(16) _Float16 tile[64][72];
    const int lt = blockIdx.x;
    const int ih = blockIdx.y;
    const int t = threadIdx.x;
    const int r = t >> 2, seg = t & 3;
    const size_t base = ((size_t)(ih * SQL + lt * 64 + r)) * HD + seg * 16;
    float v[16];
    if (*flag) {
        const unsigned short* src = (const unsigned short*)kvin + base;
        u16x8 u0 = *(const u16x8*)(src);
        u16x8 u1 = *(const u16x8*)(src + 8);
#pragma unroll
        for (int j = 0; j < 8; j++) { v[j] = bf2f(u0[j]); v[8 + j] = bf2f(u1[j]); }
    } else {
        const float* src = (const float*)kvin + base;
#pragma unroll
        for (int c = 0; c < 4; c++) {
            f32x4 a = *(const f32x4*)(src + c * 4);
#pragma unroll
            for (int j = 0; j < 4; j++) v[c * 4 + j] = a[j];
        }
    }
    half8 h0, h1;
#pragma unroll
    for (int j = 0; j < 8; j++) { h0[j] = (_Float16)v[j]; h1[j] = (_Float16)v[8 + j]; }
    _Float16* dst = kv16 + base;
    *(half8*)(dst) = h0;
    *(half8*)(dst + 8) = h1;
#pragma unroll
    for (int j = 0; j < 16; j++) tile[r][seg * 16 + j] = (_Float16)v[j];
    __syncthreads();
    half8 o0, o1;
#pragma unroll
    for (int j = 0; j < 8; j++) { o0[j] = tile[seg * 16 + j][r]; o1[j] = tile[seg * 16 + 8 + j][r]; }
    _Float16* dt = kvT16 + ((size_t)(ih * HD + r)) * SQL + lt * 64 + seg * 16;
    *(half8*)(dt) = o0;
    *(half8*)(dt + 8) = o1;
}

// ---------- prep: x (B,C,S) -> (B,S,C) f16 ----------
__global__ void prep_x(const void* __restrict__ xin, _Float16* __restrict__ x16,
                       const int* __restrict__ flag) {
    __shared__ __align__(16) _Float16 tile[64][72];
    const int st = blockIdx.x;
    const int ct = blockIdx.y;
    const int b = blockIdx.z;
    const int t = threadIdx.x;
    const int r = t >> 2, seg = t & 3;
    const size_t base = ((size_t)(b * CD + ct * 64 + r)) * SQL + st * 64 + seg * 16;
    float v[16];
    if (*flag) {
        const unsigned short* src = (const unsigned short*)xin + base;
        u16x8 u0 = *(const u16x8*)(src);
        u16x8 u1 = *(const u16x8*)(src + 8);
#pragma unroll
        for (int j = 0; j < 8; j++) { v[j] = bf2f(u0[j]); v[8 + j] = bf2f(u1[j]); }
    } else {
        const float* src = (const float*)xin + base;
#pragma unroll
        for (int c = 0; c < 4; c++) {
            f32x4 a = *(const f32x4*)(src + c * 4);
#pragma unroll
            for (int j = 0; j < 4; j++) v[c * 4 + j] = a[j];
        }
    }
#pragma unroll
    for (int j = 0; j < 16; j++) tile[r][seg * 16 + j] = (_Float16)v[j];
    __syncthreads();
    half8 o0, o1;
#pragma unroll
    for (int j = 0; j < 8; j++) { o0[j] = tile[seg * 16 + j][r]; o1[j] = tile[seg * 16 + 8 + j][r]; }
    _Float16* dt = x16 + ((size_t)(b * SQL + st * 64 + r)) * CD + ct * 64 + seg * 16;
    *(half8*)(dt) = o0;
    *(half8*)(dt + 8) = o1;
}

// ---------- prep: w -> f16 ----------
__global__ void prep_w(const void* __restrict__ win, _Float16* __restrict__ w16,
                       const int* __restrict__ flag) {
    const int i = blockIdx.x * blockDim.x + threadIdx.x;   // 8-elem chunks
    const size_t base = (size_t)i * 8;
    half8 h;
    if (*flag) {
        u16x8 u = *(const u16x8*)((const unsigned short*)win + base);
#pragma unroll
        for (int j = 0; j < 8; j++) h[j] = (_Float16)bf2f(u[j]);
    } else {
        const float* p = (const float*)win + base;
        f32x4 a0 = *(const f32x4*)(p);
        f32x4 a1 = *(const f32x4*)(p + 4);
#pragma unroll
        for (int j = 0; j < 4; j++) { h[j] = (_Float16)a0[j]; h[4 + j] = (_Float16)a1[j]; }
    }
    *(half8*)(w16 + base) = h;
}

// ---------- megakernel: all 4 layers, x resident in LDS ----------
// Block = (s-tile of 64, b); 2 waves x 32 s. Per layer: q^T = w.x^T (16x16x32,
// w frags direct from L2); QK^T and PV via 16x16x16 with q and P^T register-
// resident (C-layout == B-layout identity, proven R3/R4). kv tiles staged via
// glds dbuf + XOR swizzle (proven R4). xq LDS buffer shared by x and q^T
// (rows wave-private -> no barriers except kv staging).
__global__ __launch_bounds__(128) void mega(const _Float16* __restrict__ xg,
                                            const _Float16* __restrict__ w16,
                                            const _Float16* __restrict__ kv16,
                                            const _Float16* __restrict__ kvT16,
                                            void* __restrict__ outp,
                                            const int* __restrict__ flag) {
    __shared__ __align__(16) _Float16 xq[64 * 256];     // XOR-swizzled (8-half granules)
    __shared__ __align__(16) _Float16 kvl[2][4096];
    __shared__ __align__(16) _Float16 kvt[2][4096];
    const int st = blockIdx.x, b = blockIdx.y;
    const int t = threadIdx.x;
    const int wv = t >> 6, lane = t & 63, l16 = lane & 15, quad = lane >> 4;
    const int sw = wv * 32;                 // wave's s-offset within 64-row tile
    const int s_blk = st * 64;

    // ---- init: load x tile (64 s x 256 c) from xg into swizzled xq ----
    {
        const int row = t >> 1, colh = t & 1;
        const _Float16* src = xg + ((size_t)(b * SQL + s_blk + row) << 8);
#pragma unroll
        for (int k2 = 0; k2 < 16; k2++) {
            const int g = colh * 16 + k2;
            *(half8*)(xq + row * 256 + ((g ^ (row & 7)) * 8)) = *(const half8*)(src + g * 8);
        }
    }

    // ---- kv staging helper (flat step U = ((layer*4+h)*16 + lt)) ----
    auto stage = [&](int U) {
        const int lay = U >> 6, hh = (U >> 4) & 3, lt = U & 15;
        const int buf = U & 1;
        const size_t kvrow = ((size_t)(lay * NH + hh) << 10) + (lt << 6);  // + R
        const size_t ktrow = ((size_t)(lay * NH + hh) << 6);               // + R
        const int cc = ((lane & 7) ^ (lane >> 3)) * 8;
#pragma unroll
        for (int rep = 0; rep < 4; rep++) {
            const int R = (rep * 2 + wv) * 8 + (lane >> 3);
            const _Float16* g0 = kv16 + ((kvrow + R) << 6) + cc;
            const _Float16* g1 = kvT16 + ((ktrow + R) << 10) + (lt << 6) + cc;
            __builtin_amdgcn_global_load_lds((const __attribute__((address_space(1))) void*)g0,
                (__attribute__((address_space(3))) void*)(&kvl[buf][(rep * 2 + wv) * 512]), 16, 0, 0);
            __builtin_amdgcn_global_load_lds((const __attribute__((address_space(1))) void*)g1,
                (__attribute__((address_space(3))) void*)(&kvt[buf][(rep * 2 + wv) * 512]), 16, 0, 0);
        }
    };
    stage(0);
    __syncthreads();

    half4 qh[16][2];   // q^T frags, B-operand layout of 16x16x16 (k=d=quad*4+r)

    for (int L = 0; L < NL; L++) {
        // ---- GEMM: q^T = w . x^T, M=o 256 (16 tiles), N=s 32 (2 tiles), K=256 ----
        half8 bxa[8][2];
#pragma unroll
        for (int ks = 0; ks < 8; ks++)
#pragma unroll
            for (int nt = 0; nt < 2; nt++)
                bxa[ks][nt] = *(const half8*)(xq + (sw + nt * 16 + l16) * 256 +
                                              (((ks * 4 + quad) ^ (l16 & 7)) * 8));
        const _Float16* wb = w16 + ((size_t)L << 16);
#pragma unroll
        for (int md = 0; md < 16; md++) {
            f32x4 acc[2];
#pragma unroll
            for (int r = 0; r < 4; r++) { acc[0][r] = 0.0f; acc[1][r] = 0.0f; }
#pragma unroll
            for (int ks = 0; ks < 8; ks++) {
                half8 aw = *(const half8*)(wb + (md * 16 + l16) * 256 + ks * 32 + quad * 8);
                acc[0] = __builtin_amdgcn_mfma_f32_16x16x32_f16(aw, bxa[ks][0], acc[0], 0, 0, 0);
                acc[1] = __builtin_amdgcn_mfma_f32_16x16x32_f16(aw, bxa[ks][1], acc[1], 0, 0, 0);
            }
#pragma unroll
            for (int nt = 0; nt < 2; nt++)
#pragma unroll
                for (int r = 0; r < 4; r++) qh[md][nt][r] = (_Float16)(acc[nt][r] * 0.125f);
        }

        // ---- attention: 4 heads x 16 l-tiles ----
        for (int h = 0; h < NH; h++) {
            f32x4 oacc[4][2];
            float lsum[2] = {0.0f, 0.0f};
#pragma unroll
            for (int md = 0; md < 4; md++)
#pragma unroll
                for (int nt = 0; nt < 2; nt++)
#pragma unroll
                    for (int r = 0; r < 4; r++) oacc[md][nt][r] = 0.0f;

            for (int lt = 0; lt < 16; lt++) {
                const int U = ((L * NH + h) << 4) + lt;
                __syncthreads();
                if (U + 1 < NL * NH * 16) stage(U + 1);
                const _Float16* kl = kvl[U & 1];
                const _Float16* kt = kvt[U & 1];

                // S^T = K . q^T  (M=l 4x16, N=s 2x16, K=d in 4 steps of 16)
                f32x4 stt[4][2];
#pragma unroll
                for (int ms = 0; ms < 4; ms++)
#pragma unroll
                    for (int nt = 0; nt < 2; nt++)
#pragma unroll
                        for (int r = 0; r < 4; r++) stt[ms][nt][r] = 0.0f;
#pragma unroll
                for (int kd = 0; kd < 4; kd++)
#pragma unroll
                    for (int ms = 0; ms < 4; ms++) {
                        half4 av = *(const half4*)(kl + (ms * 16 + l16) * 64 +
                                   (((kd * 2 + (quad >> 1)) ^ (l16 & 7)) * 8) + (quad & 1) * 4);
#pragma unroll
                        for (int nt = 0; nt < 2; nt++)
                            stt[ms][nt] = __builtin_amdgcn_mfma_f32_16x16x16f16(
                                av, qh[h * 4 + kd][nt], stt[ms][nt], 0, 0, 0);
                    }
                // exp in-register -> P^T B-frags
                half4 pb[4][2];
#pragma unroll
                for (int ms = 0; ms < 4; ms++)
#pragma unroll
                    for (int nt = 0; nt < 2; nt++) {
                        float e0 = __expf(stt[ms][nt][0]);
                        float e1 = __expf(stt[ms][nt][1]);
                        float e2 = __expf(stt[ms][nt][2]);
                        float e3 = __expf(stt[ms][nt][3]);
                        lsum[nt] += (e0 + e1) + (e2 + e3);
                        half4 p; p[0] = (_Float16)e0; p[1] = (_Float16)e1;
                        p[2] = (_Float16)e2; p[3] = (_Float16)e3;
                        pb[ms][nt] = p;
                    }
                // O^T += V^T . P^T  (M=d 4x16, N=s 2x16, K=l in 4 steps of 16)
#pragma unroll
                for (int ks = 0; ks < 4; ks++)
#pragma unroll
                    for (int md = 0; md < 4; md++) {
                        half4 av = *(const half4*)(kt + (md * 16 + l16) * 64 +
                                   (((ks * 2 + (quad >> 1)) ^ (l16 & 7)) * 8) + (quad & 1) * 4);
#pragma unroll
                        for (int nt = 0; nt < 2; nt++)
                            oacc[md][nt] = __builtin_amdgcn_mfma_f32_16x16x16f16(
                                av, pb[ks][nt], oacc[md][nt], 0, 0, 0);
                    }
            }
            // normalize + write head output
            float inv[2];
#pragma unroll
            for (int nt = 0; nt < 2; nt++) {
                float v = lsum[nt];
                v += __shfl_xor(v, 16);
                v += __shfl_xor(v, 32);
                inv[nt] = 1.0f / v;
            }
            if (L < NL - 1) {
#pragma unroll
                for (int md = 0; md < 4; md++)
#pragma unroll
                    for (int nt = 0; nt < 2; nt++) {
                        const int row = sw + nt * 16 + l16;
                        const int g = h * 8 + md * 2 + (quad >> 1);
                        half4 hv;
#pragma unroll
                        for (int r = 0; r < 4; r++) hv[r] = (_Float16)(oacc[md][nt][r] * inv[nt]);
                        *(half4*)(xq + row * 256 + ((g ^ (row & 7)) * 8) + (quad & 1) * 4) = hv;
                    }
            } else if (*flag) {
#pragma unroll
                for (int md = 0; md < 4; md++)
#pragma unroll
                    for (int nt = 0; nt < 2; nt++) {
                        const int s = s_blk + sw + nt * 16 + l16;
#pragma unroll
                        for (int r = 0; r < 4; r++) {
                            const int c = (h << 6) + md * 16 + quad * 4 + r;
                            ((unsigned short*)outp)[(((size_t)(b * CD + c)) << 10) + s] =
                                f2bf(oacc[md][nt][r] * inv[nt]);
                        }
                    }
            } else {
#pragma unroll
                for (int md = 0; md < 4; md++)
#pragma unroll
                    for (int nt = 0; nt < 2; nt++) {
                        const int s = s_blk + sw + nt * 16 + l16;
#pragma unroll
                        for (int r = 0; r < 4; r++) {
                            const int c = (h << 6) + md * 16 + quad * 4 + r;
                            ((float*)outp)[(((size_t)(b * CD + c)) << 10) + s] =
                                oacc[md][nt][r] * inv[nt];
                        }
                    }
            }
        }
    }
}

extern "C" void kernel_launch(void* const* d_in, const int* in_sizes, int n_in,
                              void* d_out, int out_size, void* d_ws, size_t ws_size,
                              hipStream_t stream) {
    const void* xin = d_in[0];
    // d_in[1] = length: used only for its shape (L=1024) — values irrelevant
    const void* win = d_in[2];
    const void* kvin = d_in[3];

    char* ws = (char*)d_ws;
    const size_t MB = 1u << 20;
    _Float16* xg    = (_Float16*)(ws);               // 8 MB  (B,S,C) f16
    _Float16* w16   = (_Float16*)(ws + 8 * MB);      // 0.5 MB (NL,256,256) f16
    _Float16* kv16  = (_Float16*)(ws + 9 * MB);      // 2 MB  (NL,H,L,D) f16
    _Float16* kvT16 = (_Float16*)(ws + 11 * MB);     // 2 MB  (NL,H,D,L) f16
    int*      flag  = (int*)(ws + 13 * MB);          // 4 B   dtype flag

    detect_dtype<<<1, 64, 0, stream>>>((const unsigned int*)win, flag);
    prep_kv<<<dim3(SQL / 64, NL * NH), 256, 0, stream>>>(kvin, kv16, kvT16, flag);
    prep_x<<<dim3(SQL / 64, CD / 64, BB), 256, 0, stream>>>(xin, xg, flag);
    prep_w<<<dim3(NL * CD * CD / 8 / 256), 256, 0, stream>>>(win, w16, flag);

    mega<<<dim3(SQL / 64, BB), 128, 0, stream>>>(xg, w16, kv16, kvT16, d_out, flag);
}

// Round 7
// 249.143 us; speedup vs baseline: 2.0550x; 2.0550x over previous
//
#include <hip/hip_runtime.h>

#define NL   4
#define NH   4
#define HD   64
#define CD   256
#define SQL  1024
#define BB   16

typedef _Float16 half8 __attribute__((ext_vector_type(8)));
typedef _Float16 half4 __attribute__((ext_vector_type(4)));
typedef float    f32x4 __attribute__((ext_vector_type(4)));
typedef unsigned short u16x8 __attribute__((ext_vector_type(8)));

static __device__ __forceinline__ float bf2f(unsigned short u) {
    union { unsigned int i; float f; } v; v.i = ((unsigned int)u) << 16; return v.f;
}
static __device__ __forceinline__ unsigned short f2bf(float f) {
    union { float f; unsigned int i; } v; v.f = f;
    unsigned int u = v.i;
    return (unsigned short)((u + 0x7fffu + ((u >> 16) & 1u)) >> 16);
}

// inline dtype detect: 1 = inputs are packed bf16, 0 = f32. Uniform scalar loop.
static __device__ __forceinline__ int detect_flag(const void* win) {
    const unsigned int* w = (const unsigned int*)win;
    int cnt = 0;
#pragma unroll 1
    for (int i = 0; i < 64; i++) {
        unsigned int lo = w[i] & 0xFFFFu;
        int e = (int)((lo >> 7) & 0xFF);
        cnt += (e >= 96 && e <= 144) ? 1 : 0;
    }
    return cnt >= 48 ? 1 : 0;
}

// ---------- merged prep: x transpose+cvt | kv cvt+transpose | w cvt ----------
__global__ __launch_bounds__(256) void prep_all(const void* __restrict__ xin,
                                                const void* __restrict__ win,
                                                const void* __restrict__ kvin,
                                                _Float16* __restrict__ x16,
                                                _Float16* __restrict__ w16,
                                                _Float16* __restrict__ kv16,
                                                _Float16* __restrict__ kvT16) {
    __shared__ __align__(16) _Float16 tile[64][72];
    const int bi = blockIdx.x;
    const int t = threadIdx.x;
    const int isbf = detect_flag(win);

    if (bi < 1024) {
        // ---- prep_x: (B,C,S) -> (B,S,C) f16 ----
        const int st = bi & 15, ct = (bi >> 4) & 3, b = bi >> 6;
        const int r = t >> 2, seg = t & 3;
        const size_t base = ((size_t)(b * CD + ct * 64 + r)) * SQL + st * 64 + seg * 16;
        float v[16];
        if (isbf) {
            const unsigned short* src = (const unsigned short*)xin + base;
            u16x8 u0 = *(const u16x8*)(src);
            u16x8 u1 = *(const u16x8*)(src + 8);
#pragma unroll
            for (int j = 0; j < 8; j++) { v[j] = bf2f(u0[j]); v[8 + j] = bf2f(u1[j]); }
        } else {
            const float* src = (const float*)xin + base;
#pragma unroll
            for (int c = 0; c < 4; c++) {
                f32x4 a = *(const f32x4*)(src + c * 4);
#pragma unroll
                for (int j = 0; j < 4; j++) v[c * 4 + j] = a[j];
            }
        }
#pragma unroll
        for (int j = 0; j < 16; j++) tile[r][seg * 16 + j] = (_Float16)v[j];
        __syncthreads();
        half8 o0, o1;
#pragma unroll
        for (int j = 0; j < 8; j++) { o0[j] = tile[seg * 16 + j][r]; o1[j] = tile[seg * 16 + 8 + j][r]; }
        _Float16* dt = x16 + ((size_t)(b * SQL + st * 64 + r)) * CD + ct * 64 + seg * 16;
        *(half8*)(dt) = o0;
        *(half8*)(dt + 8) = o1;
    } else if (bi < 1280) {
        // ---- prep_kv: cvt copy + transposed copy ----
        const int j2 = bi - 1024;
        const int lt = j2 & 15, ih = j2 >> 4;
        const int r = t >> 2, seg = t & 3;
        const size_t base = ((size_t)(ih * SQL + lt * 64 + r)) * HD + seg * 16;
        float v[16];
        if (isbf) {
            const unsigned short* src = (const unsigned short*)kvin + base;
            u16x8 u0 = *(const u16x8*)(src);
            u16x8 u1 = *(const u16x8*)(src + 8);
#pragma unroll
            for (int j = 0; j < 8; j++) { v[j] = bf2f(u0[j]); v[8 + j] = bf2f(u1[j]); }
        } else {
            const float* src = (const float*)kvin + base;
#pragma unroll
            for (int c = 0; c < 4; c++) {
                f32x4 a = *(const f32x4*)(src + c * 4);
#pragma unroll
                for (int j = 0; j < 4; j++) v[c * 4 + j] = a[j];
            }
        }
        half8 h0, h1;
#pragma unroll
        for (int j = 0; j < 8; j++) { h0[j] = (_Float16)v[j]; h1[j] = (_Float16)v[8 + j]; }
        _Float16* dst = kv16 + base;
        *(half8*)(dst) = h0;
        *(half8*)(dst + 8) = h1;
#pragma unroll
        for (int j = 0; j < 16; j++) tile[r][seg * 16 + j] = (_Float16)v[j];
        __syncthreads();
        half8 o0, o1;
#pragma unroll
        for (int j = 0; j < 8; j++) { o0[j] = tile[seg * 16 + j][r]; o1[j] = tile[seg * 16 + 8 + j][r]; }
        _Float16* dt = kvT16 + ((size_t)(ih * HD + r)) * SQL + lt * 64 + seg * 16;
        *(half8*)(dt) = o0;
        *(half8*)(dt + 8) = o1;
    } else {
        // ---- prep_w: elementwise cvt ----
        const int i = (bi - 1280) * 256 + t;           // 8-elem chunks
        const size_t base = (size_t)i * 8;
        half8 h;
        if (isbf) {
            u16x8 u = *(const u16x8*)((const unsigned short*)win + base);
#pragma unroll
            for (int j = 0; j < 8; j++) h[j] = (_Float16)bf2f(u[j]);
        } else {
            const float* p = (const float*)win + base;
            f32x4 a0 = *(const f32x4*)(p);
            f32x4 a1 = *(const f32x4*)(p + 4);
#pragma unroll
            for (int j = 0; j < 4; j++) { h[j] = (_Float16)a0[j]; h[4 + j] = (_Float16)a1[j]; }
        }
        *(half8*)(w16 + base) = h;
    }
}

// ---------- fused layer: LDS-free gemm (q in registers) + flash attention ----------
// Grid (8 s-tiles, NH, BB), 256 threads. gemm: q^T = w.x^T via 16x16x32, w/x
// frags straight from global (k-contiguous rows), zero barriers; q C-frags
// feed QK^T 16x16x16 as B-operand (register identity, validated R5-mega).
// Attention: R4's validated kv dbuf (glds width-16 + XOR swizzle), register
// P^T, exp2 with log2e pre-folded into q scale.
__global__ __launch_bounds__(256) void layer_fused(const _Float16* __restrict__ xg,
                                                   _Float16* __restrict__ xout,
                                                   const _Float16* __restrict__ w16,
                                                   const _Float16* __restrict__ kv16,
                                                   const _Float16* __restrict__ kvT16,
                                                   const void* __restrict__ win,
                                                   void* __restrict__ outp,
                                                   int L) {
    __shared__ __align__(16) _Float16 kvl[2][4096];
    __shared__ __align__(16) _Float16 kvt[2][4096];
    const int sb = blockIdx.x;
    const int h  = blockIdx.y;
    const int b  = blockIdx.z;
    const int t  = threadIdx.x;
    const int wv = t >> 6, lane = t & 63, l16 = lane & 15, quad = lane >> 4;
    const int s0 = sb * 128 + wv * 32;        // wave's 32 s-columns

    const int cc = ((lane & 7) ^ (lane >> 3)) * 8;
    const size_t kvrow = ((size_t)(L * NH + h)) << 10;   // + lt*64 + R
    const size_t ktrow = ((size_t)(L * NH + h)) << 6;    // + R

    auto stage = [&](int lt) {
        const int buf = lt & 1;
#pragma unroll
        for (int rep = 0; rep < 2; rep++) {
            const int grp = wv * 2 + rep;                 // 0..7
            const int R = grp * 8 + (lane >> 3);
            const _Float16* g0 = kv16 + ((kvrow + (lt << 6) + R) << 6) + cc;
            const _Float16* g1 = kvT16 + ((ktrow + R) << 10) + (lt << 6) + cc;
            __builtin_amdgcn_global_load_lds((const __attribute__((address_space(1))) void*)g0,
                (__attribute__((address_space(3))) void*)(&kvl[buf][grp * 512]), 16, 0, 0);
            __builtin_amdgcn_global_load_lds((const __attribute__((address_space(1))) void*)g1,
                (__attribute__((address_space(3))) void*)(&kvt[buf][grp * 512]), 16, 0, 0);
        }
    };
    stage(0);   // overlaps with the gemm below

    // ---- gemm: q^T[d=64][s=32] for this head, registers only ----
    f32x4 gacc[4][2];
#pragma unroll
    for (int md = 0; md < 4; md++)
#pragma unroll
        for (int nt = 0; nt < 2; nt++)
#pragma unroll
            for (int r = 0; r < 4; r++) gacc[md][nt][r] = 0.0f;
    const _Float16* wb = w16 + ((size_t)L << 16) + ((size_t)(h * 64) << 8);
#pragma unroll
    for (int kk = 0; kk < 8; kk++) {
        half8 bx[2];
#pragma unroll
        for (int nt = 0; nt < 2; nt++)
            bx[nt] = *(const half8*)(xg + ((size_t)((b << 10) + s0 + nt * 16 + l16) << 8) +
                                     kk * 32 + quad * 8);
#pragma unroll
        for (int md = 0; md < 4; md++) {
            half8 aw = *(const half8*)(wb + ((size_t)(md * 16 + l16) << 8) + kk * 32 + quad * 8);
            gacc[md][0] = __builtin_amdgcn_mfma_f32_16x16x32_f16(aw, bx[0], gacc[md][0], 0, 0, 0);
            gacc[md][1] = __builtin_amdgcn_mfma_f32_16x16x32_f16(aw, bx[1], gacc[md][1], 0, 0, 0);
        }
    }
    // q scale: 1/sqrt(64) * log2(e)  (exp2 later == softmax exp)
    half4 qh[4][2];
#pragma unroll
    for (int md = 0; md < 4; md++)
#pragma unroll
        for (int nt = 0; nt < 2; nt++)
#pragma unroll
            for (int r = 0; r < 4; r++)
                qh[md][nt][r] = (_Float16)(gacc[md][nt][r] * 0.180336880111120f);

    // ---- attention over 16 l-tiles ----
    f32x4 oacc[4][2];
    float lsum[2] = {0.0f, 0.0f};
#pragma unroll
    for (int md = 0; md < 4; md++)
#pragma unroll
        for (int nt = 0; nt < 2; nt++)
#pragma unroll
            for (int r = 0; r < 4; r++) oacc[md][nt][r] = 0.0f;

    for (int lt = 0; lt < 16; lt++) {
        __syncthreads();                       // drains stage(lt) glds
        if (lt + 1 < 16) stage(lt + 1);
        const _Float16* kl = kvl[lt & 1];
        const _Float16* kt = kvt[lt & 1];

        // S^T = K . q^T : M=l 4x16, N=s 2x16, K=d in 4 steps of 16
        f32x4 stt[4][2];
#pragma unroll
        for (int ms = 0; ms < 4; ms++)
#pragma unroll
            for (int nt = 0; nt < 2; nt++)
#pragma unroll
                for (int r = 0; r < 4; r++) stt[ms][nt][r] = 0.0f;
#pragma unroll
        for (int kd = 0; kd < 4; kd++)
#pragma unroll
            for (int ms = 0; ms < 4; ms++) {
                half4 av = *(const half4*)(kl + (ms * 16 + l16) * 64 +
                           (((kd * 2 + (quad >> 1)) ^ (l16 & 7)) * 8) + (quad & 1) * 4);
#pragma unroll
                for (int nt = 0; nt < 2; nt++)
                    stt[ms][nt] = __builtin_amdgcn_mfma_f32_16x16x16f16(
                        av, qh[kd][nt], stt[ms][nt], 0, 0, 0);
            }

        // exp2 in-register -> P^T B-frags (v_exp_f32 is natively base-2)
        half4 pb[4][2];
#pragma unroll
        for (int ms = 0; ms < 4; ms++)
#pragma unroll
            for (int nt = 0; nt < 2; nt++) {
                float e0 = __builtin_amdgcn_exp2f(stt[ms][nt][0]);
                float e1 = __builtin_amdgcn_exp2f(stt[ms][nt][1]);
                float e2 = __builtin_amdgcn_exp2f(stt[ms][nt][2]);
                float e3 = __builtin_amdgcn_exp2f(stt[ms][nt][3]);
                lsum[nt] += (e0 + e1) + (e2 + e3);
                half4 p; p[0] = (_Float16)e0; p[1] = (_Float16)e1;
                p[2] = (_Float16)e2; p[3] = (_Float16)e3;
                pb[ms][nt] = p;
            }

        // O^T += V^T . P^T : M=d 4x16, N=s 2x16, K=l in 4 steps of 16
#pragma unroll
        for (int ks = 0; ks < 4; ks++)
#pragma unroll
            for (int md = 0; md < 4; md++) {
                half4 av = *(const half4*)(kt + (md * 16 + l16) * 64 +
                           (((ks * 2 + (quad >> 1)) ^ (l16 & 7)) * 8) + (quad & 1) * 4);
#pragma unroll
                for (int nt = 0; nt < 2; nt++)
                    oacc[md][nt] = __builtin_amdgcn_mfma_f32_16x16x16f16(
                        av, pb[ks][nt], oacc[md][nt], 0, 0, 0);
            }
    }

    // ---- normalize + store ----
    float inv[2];
#pragma unroll
    for (int nt = 0; nt < 2; nt++) {
        float v = lsum[nt];
        v += __shfl_xor(v, 16);
        v += __shfl_xor(v, 32);
        inv[nt] = 1.0f / v;
    }

    if (L < NL - 1) {
#pragma unroll
        for (int md = 0; md < 4; md++)
#pragma unroll
            for (int nt = 0; nt < 2; nt++) {
                const int s = s0 + nt * 16 + l16;
                half4 hv;
#pragma unroll
                for (int r = 0; r < 4; r++) hv[r] = (_Float16)(oacc[md][nt][r] * inv[nt]);
                *(half4*)(xout + (((size_t)((b << 10) + s)) << 8) + (h << 6) + md * 16 + quad * 4) = hv;
            }
    } else if (detect_flag(win)) {
#pragma unroll
        for (int md = 0; md < 4; md++)
#pragma unroll
            for (int nt = 0; nt < 2; nt++) {
                const int s = s0 + nt * 16 + l16;
#pragma unroll
                for (int r = 0; r < 4; r++) {
                    const int c = (h << 6) + md * 16 + quad * 4 + r;
                    ((unsigned short*)outp)[(((size_t)(b * CD + c)) << 10) + s] =
                        f2bf(oacc[md][nt][r] * inv[nt]);
                }
            }
    } else {
#pragma unroll
        for (int md = 0; md < 4; md++)
#pragma unroll
            for (int nt = 0; nt < 2; nt++) {
                const int s = s0 + nt * 16 + l16;
#pragma unroll
                for (int r = 0; r < 4; r++) {
                    const int c = (h << 6) + md * 16 + quad * 4 + r;
                    ((float*)outp)[(((size_t)(b * CD + c)) << 10) + s] =
                        oacc[md][nt][r] * inv[nt];
                }
            }
    }
}

extern "C" void kernel_launch(void* const* d_in, const int* in_sizes, int n_in,
                              void* d_out, int out_size, void* d_ws, size_t ws_size,
                              hipStream_t stream) {
    const void* xin = d_in[0];
    // d_in[1] = length: used only for its shape (L=1024) — values irrelevant
    const void* win = d_in[2];
    const void* kvin = d_in[3];

    char* ws = (char*)d_ws;
    const size_t MB = 1u << 20;
    _Float16* xa    = (_Float16*)(ws);               // 8 MB  (B,S,C) f16
    _Float16* xb    = (_Float16*)(ws + 8 * MB);      // 8 MB  ping-pong
    _Float16* w16   = (_Float16*)(ws + 16 * MB);     // 0.5 MB
    _Float16* kv16  = (_Float16*)(ws + 17 * MB);     // 2 MB  (NL,H,L,D)
    _Float16* kvT16 = (_Float16*)(ws + 19 * MB);     // 2 MB  (NL,H,D,L)

    prep_all<<<dim3(1024 + 256 + 128), 256, 0, stream>>>(xin, win, kvin, xa, w16, kv16, kvT16);

    _Float16* cur = xa;
    _Float16* nxt = xb;
    for (int i = 0; i < NL; i++) {
        layer_fused<<<dim3(SQL / 128, NH, BB), 256, 0, stream>>>(cur, nxt, w16, kv16, kvT16,
                                                                 win, d_out, i);
        _Float16* tmp = cur; cur = nxt; nxt = tmp;
    }
}